// Round 1
// baseline (238.545 us; speedup 1.0000x reference)
//
#include <hip/hip_runtime.h>

typedef __bf16 bf16;
typedef __bf16 bf16x8 __attribute__((ext_vector_type(8)));
typedef __bf16 bf16x4 __attribute__((ext_vector_type(4)));
typedef float f32x4 __attribute__((ext_vector_type(4)));

#define NB 2
#define NQ 2048
#define NKK 2048
#define NC 512
#define NH 8
#define ND 64
#define NM (NB*NQ)   // 4096 rows

// ---------------- pass 0a: f32 -> bf16 ----------------
__global__ __launch_bounds__(256) void cvt_bf16_kernel(const float* __restrict__ in,
                                                       bf16* __restrict__ out, int n4) {
  int i = blockIdx.x * 256 + threadIdx.x;
  if (i < n4) {
    float4 v = ((const float4*)in)[i];
    bf16x4 o;
    o[0] = (bf16)v.x; o[1] = (bf16)v.y; o[2] = (bf16)v.z; o[3] = (bf16)v.w;
    ((bf16x4*)out)[i] = o;
  }
}

// ---------------- pass 0b: W[512][512] f32 -> WT[n][k] bf16 ----------------
__global__ __launch_bounds__(256) void transpose_w_kernel(const float* __restrict__ W,
                                                          bf16* __restrict__ WT) {
  __shared__ float t[32][33];
  int n0 = blockIdx.x * 32, k0 = blockIdx.y * 32;
  int c = threadIdx.x & 31, r0 = threadIdx.x >> 5;
  for (int r = r0; r < 32; r += 8) t[r][c] = W[(size_t)(k0 + r) * NC + n0 + c];
  __syncthreads();
  for (int r = r0; r < 32; r += 8) WT[(size_t)(n0 + r) * NC + k0 + c] = (bf16)t[c][r];
}

// ---------------- pass 1/3: GEMM  Y[M][512] = X[M][512] @ WT^T, fused epilogues ----------------
// epi: 0=Q (scale 1/8 -> qh[b][h][q][d])  1=K -> kh  2=V -> vh  3=G (sigmoid+bg -> f32)  4=O (+bo -> f32 d_out)
__global__ __launch_bounds__(256) void gemm_kernel(const bf16* __restrict__ X,
                                                   const bf16* __restrict__ WT,
                                                   const float* __restrict__ bias,
                                                   void* __restrict__ out, int epi) {
  __shared__ bf16 Xs[64][72];
  __shared__ bf16 Ws[64][72];
  int m0 = blockIdx.y * 64, n0 = blockIdx.x * 64;
  int tid = threadIdx.x, lane = tid & 63, wave = tid >> 6;
  int wm = wave >> 1, wn = wave & 1;
  int lr = lane & 15, lg = lane >> 4;
  f32x4 acc[2][2] = {};
  for (int k0 = 0; k0 < 512; k0 += 64) {
#pragma unroll
    for (int j = 0; j < 2; j++) {
      int cc = tid + 256 * j;
      int r = cc >> 3, c8 = (cc & 7) * 8;
      *(uint4*)&Xs[r][c8] = *(const uint4*)&X[(size_t)(m0 + r) * 512 + k0 + c8];
      *(uint4*)&Ws[r][c8] = *(const uint4*)&WT[(size_t)(n0 + r) * 512 + k0 + c8];
    }
    __syncthreads();
#pragma unroll
    for (int kk = 0; kk < 64; kk += 32) {
      bf16x8 a[2], b[2];
      a[0] = *(const bf16x8*)&Xs[wm * 32 + lr][kk + lg * 8];
      a[1] = *(const bf16x8*)&Xs[wm * 32 + 16 + lr][kk + lg * 8];
      b[0] = *(const bf16x8*)&Ws[wn * 32 + lr][kk + lg * 8];
      b[1] = *(const bf16x8*)&Ws[wn * 32 + 16 + lr][kk + lg * 8];
#pragma unroll
      for (int mi = 0; mi < 2; mi++)
#pragma unroll
        for (int ni = 0; ni < 2; ni++)
          acc[mi][ni] = __builtin_amdgcn_mfma_f32_16x16x32_bf16(a[mi], b[ni], acc[mi][ni], 0, 0, 0);
    }
    __syncthreads();
  }
#pragma unroll
  for (int mi = 0; mi < 2; mi++) {
#pragma unroll
    for (int ni = 0; ni < 2; ni++) {
#pragma unroll
      for (int i = 0; i < 4; i++) {
        int grow = m0 + wm * 32 + mi * 16 + lg * 4 + i;
        int gcol = n0 + wn * 32 + ni * 16 + lr;
        float v = acc[mi][ni][i];
        if (epi == 0) {
          int b = grow >> 11, q = grow & 2047, h = gcol >> 6, d = gcol & 63;
          ((bf16*)out)[((size_t)(b * NH + h) * NQ + q) * ND + d] = (bf16)(v * 0.125f);
        } else if (epi == 1 || epi == 2) {
          int b = grow >> 11, kq = grow & 2047, h = gcol >> 6, d = gcol & 63;
          ((bf16*)out)[((size_t)(b * NH + h) * NKK + kq) * ND + d] = (bf16)v;
        } else if (epi == 3) {
          v += bias[gcol];
          v = 1.0f / (1.0f + __expf(-v));
          ((float*)out)[(size_t)grow * 512 + gcol] = v;
        } else {
          ((float*)out)[(size_t)grow * 512 + gcol] = v + bias[gcol];
        }
      }
    }
  }
}

// ---------------- pass 1.5: vh[b][h][k][d] -> vT[b][h][d][k] ----------------
__global__ __launch_bounds__(256) void transpose_v_kernel(const bf16* __restrict__ vh,
                                                          bf16* __restrict__ vT) {
  __shared__ bf16 t[64][72];
  int bh = blockIdx.y;
  int kk0 = blockIdx.x * 64;
  const bf16* src = vh + (size_t)bh * NKK * ND;
  bf16* dst = vT + (size_t)bh * ND * NKK;
#pragma unroll
  for (int j = 0; j < 2; j++) {
    int c = threadIdx.x + 256 * j;
    int r = c >> 3, cc = (c & 7) * 8;
    *(uint4*)&t[r][cc] = *(const uint4*)&src[(size_t)(kk0 + r) * ND + cc];
  }
  __syncthreads();
#pragma unroll
  for (int j = 0; j < 2; j++) {
    int c = threadIdx.x + 256 * j;
    int d = c >> 3, ck = (c & 7) * 8;
    bf16 tmp[8];
#pragma unroll
    for (int x = 0; x < 8; x++) tmp[x] = t[ck + x][d];
    *(uint4*)&dst[(size_t)d * NKK + kk0 + ck] = *(const uint4*)tmp;
  }
}

// ---------------- pass 2: fused flash attention ----------------
// grid (128, 2): one WG = (b, 16-row q-tile); 8 waves = 8 heads.
struct Tile {
  float b1v[2][4];
  float b2v[2][4];
  bf16x8 kf[2][2];
  bf16x8 vf[4];
};

__device__ __forceinline__ void load_tile(int k0, const float* __restrict__ b1,
                                          const float* __restrict__ b2,
                                          const bf16* __restrict__ Kp,
                                          const bf16* __restrict__ Vt,
                                          int lr, int lg, Tile& T) {
#pragma unroll
  for (int f = 0; f < 2; f++) {
#pragma unroll
    for (int i = 0; i < 4; i++) {
      int row = lg * 4 + i;
      int col = k0 + f * 16 + lr;
      T.b1v[f][i] = b1[row * NKK + col];
      T.b2v[f][i] = b2[row * NKK + col];
    }
  }
#pragma unroll
  for (int f = 0; f < 2; f++) {
#pragma unroll
    for (int kc = 0; kc < 2; kc++)
      T.kf[f][kc] = *(const bf16x8*)&Kp[(size_t)(k0 + f * 16 + lr) * ND + kc * 32 + lg * 8];
  }
#pragma unroll
  for (int ni = 0; ni < 4; ni++)
    T.vf[ni] = *(const bf16x8*)&Vt[(size_t)(ni * 16 + lr) * NKK + k0 + lg * 8];
}

__device__ __forceinline__ void compute_tile(const Tile& T, bf16x8 qf0, bf16x8 qf1,
                                             f32x4 (&o)[4], float (&mrow)[4], float (&lrow)[4],
                                             bf16 (*pl)[40], int lr, int lg) {
  f32x4 s[2];
#pragma unroll
  for (int f = 0; f < 2; f++) {
    f32x4 c;
#pragma unroll
    for (int i = 0; i < 4; i++) c[i] = T.b1v[f][i] + T.b2v[f][i];
    c = __builtin_amdgcn_mfma_f32_16x16x32_bf16(qf0, T.kf[f][0], c, 0, 0, 0);
    c = __builtin_amdgcn_mfma_f32_16x16x32_bf16(qf1, T.kf[f][1], c, 0, 0, 0);
    s[f] = c;
  }
  float scal[4];
#pragma unroll
  for (int i = 0; i < 4; i++) {
    float t = fmaxf(s[0][i], s[1][i]);
    t = fmaxf(t, __shfl_xor(t, 1));
    t = fmaxf(t, __shfl_xor(t, 2));
    t = fmaxf(t, __shfl_xor(t, 4));
    t = fmaxf(t, __shfl_xor(t, 8));
    float mn = fmaxf(mrow[i], t);
    scal[i] = __expf(mrow[i] - mn);
    mrow[i] = mn;
    float p0 = __expf(s[0][i] - mn);
    float p1 = __expf(s[1][i] - mn);
    s[0][i] = p0; s[1][i] = p1;
    float ts = p0 + p1;
    ts += __shfl_xor(ts, 1);
    ts += __shfl_xor(ts, 2);
    ts += __shfl_xor(ts, 4);
    ts += __shfl_xor(ts, 8);
    lrow[i] = lrow[i] * scal[i] + ts;
  }
#pragma unroll
  for (int ni = 0; ni < 4; ni++)
#pragma unroll
    for (int i = 0; i < 4; i++) o[ni][i] *= scal[i];
  // P (C-layout) -> per-wave LDS -> A-layout fragment
#pragma unroll
  for (int f = 0; f < 2; f++)
#pragma unroll
    for (int i = 0; i < 4; i++) pl[lg * 4 + i][f * 16 + lr] = (bf16)s[f][i];
  bf16x8 pa = *(const bf16x8*)&pl[lr][lg * 8];
#pragma unroll
  for (int ni = 0; ni < 4; ni++)
    o[ni] = __builtin_amdgcn_mfma_f32_16x16x32_bf16(pa, T.vf[ni], o[ni], 0, 0, 0);
}

__global__ __launch_bounds__(512, 2) void attn_kernel(
    const bf16* __restrict__ qh, const bf16* __restrict__ kh, const bf16* __restrict__ vT,
    const float* __restrict__ bias1, const float* __restrict__ bias2,
    const float* __restrict__ gate, bf16* __restrict__ ao) {
  __shared__ bf16 plds[8][16][40];
  int b = blockIdx.y, q0 = blockIdx.x * 16;
  int h = threadIdx.x >> 6, lane = threadIdx.x & 63;
  int lr = lane & 15, lg = lane >> 4;
  const bf16* Qp = qh + ((size_t)(b * NH + h) * NQ + q0) * ND;
  const bf16* Kp = kh + (size_t)(b * NH + h) * NKK * ND;
  const bf16* Vt = vT + (size_t)(b * NH + h) * ND * NKK;
  const float* b1 = bias1 + ((size_t)b * NQ + q0) * NKK;
  const float* b2 = bias2 + ((size_t)h * NQ + q0) * NKK;

  bf16x8 qf0 = *(const bf16x8*)&Qp[lr * 64 + lg * 8];
  bf16x8 qf1 = *(const bf16x8*)&Qp[lr * 64 + 32 + lg * 8];

  f32x4 o[4] = {};
  float mrow[4] = {-1e30f, -1e30f, -1e30f, -1e30f};
  float lrow[4] = {0.f, 0.f, 0.f, 0.f};
  bf16(*pl)[40] = plds[h];

  Tile TA, TB;
  load_tile(0, b1, b2, Kp, Vt, lr, lg, TA);
  for (int t = 0; t < 64; t += 2) {
    load_tile((t + 1) * 32, b1, b2, Kp, Vt, lr, lg, TB);
    compute_tile(TA, qf0, qf1, o, mrow, lrow, pl, lr, lg);
    if (t + 2 < 64) load_tile((t + 2) * 32, b1, b2, Kp, Vt, lr, lg, TA);
    compute_tile(TB, qf0, qf1, o, mrow, lrow, pl, lr, lg);
  }

  float inv[4];
#pragma unroll
  for (int i = 0; i < 4; i++) inv[i] = 1.0f / lrow[i];
#pragma unroll
  for (int ni = 0; ni < 4; ni++) {
#pragma unroll
    for (int i = 0; i < 4; i++) {
      int q = q0 + lg * 4 + i;
      int d = ni * 16 + lr;
      size_t idx = ((size_t)b * NQ + q) * 512 + h * 64 + d;
      float g = gate[idx];
      ao[idx] = (bf16)(o[ni][i] * inv[i] * g);
    }
  }
}

// ---------------- host launch ----------------
extern "C" void kernel_launch(void* const* d_in, const int* in_sizes, int n_in,
                              void* d_out, int out_size, void* d_ws, size_t ws_size,
                              hipStream_t stream) {
  const float* query = (const float*)d_in[0];
  const float* keyd  = (const float*)d_in[1];
  const float* bias1 = (const float*)d_in[2];
  const float* bias2 = (const float*)d_in[3];
  const float* wq = (const float*)d_in[4];
  const float* wk = (const float*)d_in[5];
  const float* wv = (const float*)d_in[6];
  const float* wo = (const float*)d_in[7];
  const float* bo = (const float*)d_in[8];
  const float* wg = (const float*)d_in[9];
  const float* bg = (const float*)d_in[10];

  char* ws = (char*)d_ws;
  size_t off = 0;
  auto alloc = [&](size_t bytes) {
    void* p = ws + off;
    off += (bytes + 255) & ~(size_t)255;
    return p;
  };
  bf16* qd_bf = (bf16*)alloc((size_t)NM * 512 * 2);
  bf16* kd_bf = (bf16*)alloc((size_t)NM * 512 * 2);
  bf16* wqT = (bf16*)alloc((size_t)512 * 512 * 2);
  bf16* wkT = (bf16*)alloc((size_t)512 * 512 * 2);
  bf16* wvT = (bf16*)alloc((size_t)512 * 512 * 2);
  bf16* wgT = (bf16*)alloc((size_t)512 * 512 * 2);
  bf16* woT = (bf16*)alloc((size_t)512 * 512 * 2);
  bf16* qh  = (bf16*)alloc((size_t)NB * NH * NQ * ND * 2);
  bf16* kh  = (bf16*)alloc((size_t)NB * NH * NKK * ND * 2);
  bf16* vh  = (bf16*)alloc((size_t)NB * NH * NKK * ND * 2);
  bf16* vTt = (bf16*)alloc((size_t)NB * NH * ND * NKK * 2);
  float* gbuf = (float*)alloc((size_t)NM * 512 * 4);
  bf16* aob = (bf16*)alloc((size_t)NM * 512 * 2);

  int n4 = NM * 512 / 4;
  cvt_bf16_kernel<<<dim3(n4 / 256), 256, 0, stream>>>(query, qd_bf, n4);
  cvt_bf16_kernel<<<dim3(n4 / 256), 256, 0, stream>>>(keyd, kd_bf, n4);

  transpose_w_kernel<<<dim3(16, 16), 256, 0, stream>>>(wq, wqT);
  transpose_w_kernel<<<dim3(16, 16), 256, 0, stream>>>(wk, wkT);
  transpose_w_kernel<<<dim3(16, 16), 256, 0, stream>>>(wv, wvT);
  transpose_w_kernel<<<dim3(16, 16), 256, 0, stream>>>(wg, wgT);
  transpose_w_kernel<<<dim3(16, 16), 256, 0, stream>>>(wo, woT);

  gemm_kernel<<<dim3(8, 64), 256, 0, stream>>>(qd_bf, wqT, nullptr, qh, 0);
  gemm_kernel<<<dim3(8, 64), 256, 0, stream>>>(kd_bf, wkT, nullptr, kh, 1);
  gemm_kernel<<<dim3(8, 64), 256, 0, stream>>>(kd_bf, wvT, nullptr, vh, 2);
  gemm_kernel<<<dim3(8, 64), 256, 0, stream>>>(qd_bf, wgT, bg, gbuf, 3);

  transpose_v_kernel<<<dim3(32, 16), 256, 0, stream>>>(vh, vTt);

  attn_kernel<<<dim3(128, 2), 512, 0, stream>>>(qh, kh, vTt, bias1, bias2, gbuf, aob);

  gemm_kernel<<<dim3(8, 64), 256, 0, stream>>>(aob, woT, bo, d_out, 4);
}